// Round 9
// baseline (70.175 us; speedup 1.0000x reference)
//
#include <hip/hip_runtime.h>

#define NPTS 32768
#define NIC  16384
#define GRID 256
#define BLK  256
#define NW   4

typedef __attribute__((ext_vector_type(8))) _Float16 f16x8;
typedef __attribute__((ext_vector_type(4))) float f32x4;

// element-index XOR swizzle keyed on LDS row (row stride = 128 f16 = 256 B)
#define SWZ(e, r) ((e) ^ (((r) & 7) << 3))
#define MFMA16 __builtin_amdgcn_mfma_f32_16x16x32_f16
#define VMCNT0 asm volatile("s_waitcnt vmcnt(0)" ::: "memory")

__device__ __forceinline__ float tanh_fast(float x) {
    float e = __expf(2.0f * x);
    return 1.0f - 2.0f / (e + 1.0f);
}

__device__ __forceinline__ float wave_allsum(float v) {
#pragma unroll
    for (int off = 32; off > 0; off >>= 1) v += __shfl_xor(v, off, 64);
    return v;
}

__device__ __forceinline__ unsigned short f2hb(float x) {
    return __builtin_bit_cast(unsigned short, (_Float16)x);
}
__device__ __forceinline__ uint2 pack4h(float a, float b, float c, float d) {
    return make_uint2((unsigned)f2hb(a) | ((unsigned)f2hb(b) << 16),
                      (unsigned)f2hb(c) | ((unsigned)f2hb(d) << 16));
}

// async global -> LDS stage of one 32 KB packed weight matrix (256 threads x 8 x 16B)
__device__ __forceinline__ void stage_w_async(const unsigned short* __restrict__ src,
                                              _Float16* dst, int tid) {
    const unsigned int* gp = (const unsigned int*)src;
    unsigned int* lp = (unsigned int*)dst;
#pragma unroll
    for (int k = 0; k < 8; k++) {
        __builtin_amdgcn_global_load_lds(
            (const __attribute__((address_space(1))) unsigned int*)(gp + (tid + k * BLK) * 4),
            (__attribute__((address_space(3))) unsigned int*)(lp + (tid + k * BLK) * 4),
            16, 0, 0);
    }
}

// ---------------- prep (proven): transpose + fp16 + swizzle ----------------
__global__ __launch_bounds__(512) void k_prep(
    const float* __restrict__ mw1, const float* __restrict__ mw2,
    const float* __restrict__ nw1, const float* __restrict__ nw2,
    const float* __restrict__ mw3,
    unsigned short* __restrict__ wt1, unsigned short* __restrict__ wt2,
    unsigned short* __restrict__ nt1, unsigned short* __restrict__ nt2,
    unsigned short* __restrict__ w3t) {
    const int tid = threadIdx.x;
    const int bk = blockIdx.x;
    if (bk == 4) {
        for (int i = tid; i < 2048; i += 512) w3t[i] = 0;
        __syncthreads();
        if (tid < 512) {
            const int j = tid & 127, k = tid >> 7;
            w3t[k * 128 + SWZ(j, k)] = f2hb(mw3[j * 4 + k]);
        }
        return;
    }
    const float* src = (bk == 0) ? mw1 : (bk == 1) ? mw2 : (bk == 2) ? nw1 : nw2;
    unsigned short* dst = (bk == 0) ? wt1 : (bk == 1) ? wt2 : (bk == 2) ? nt1 : nt2;
    __shared__ float sM[128 * 129];
#pragma unroll
    for (int k = 0; k < 32; k++) {
        const int idx = tid + k * 512;
        const int j = idx >> 7, n = idx & 127;
        sM[n * 129 + j] = src[idx];
    }
    __syncthreads();
#pragma unroll
    for (int k = 0; k < 32; k++) {
        const int d = tid + k * 512;
        const int n = d >> 7, js = d & 127;
        const int j = js ^ ((n & 7) << 3);
        dst[d] = f2hb(sM[n * 129 + j]);
    }
}

// value-only hidden layer over 64 points (4 pt-tiles), wave = 32-row tile.
// Ends with: barrier; optional async stage of nextW into sWdst; epilogue H writes.
// Caller must do VMCNT0 + __syncthreads() before next consumer.
__device__ __forceinline__ void hidden_val(const _Float16* sW, _Float16* sHv,
                                           const float* bias,
                                           const unsigned short* nextW, _Float16* sWdst,
                                           int tid, int wv, int g, int l15) {
    f32x4 acc[2][4];
#pragma unroll
    for (int rr = 0; rr < 2; rr++)
#pragma unroll
        for (int pt = 0; pt < 4; pt++) acc[rr][pt] = (f32x4){0.f, 0.f, 0.f, 0.f};
#pragma unroll
    for (int ks = 0; ks < 4; ks++) {
        const int ee = SWZ(ks * 32 + g * 8, l15);
        const f16x8 A0 = *(const f16x8*)&sW[(wv * 32 + l15) * 128 + ee];
        const f16x8 A1 = *(const f16x8*)&sW[(wv * 32 + 16 + l15) * 128 + ee];
#pragma unroll
        for (int pt = 0; pt < 4; pt++) {
            const f16x8 Bv = *(const f16x8*)&sHv[(pt * 16 + l15) * 128 + ee];
            acc[0][pt] = MFMA16(A0, Bv, acc[0][pt], 0, 0, 0);
            acc[1][pt] = MFMA16(A1, Bv, acc[1][pt], 0, 0, 0);
        }
    }
    __syncthreads();  // all sW & sHv reads complete
    if (nextW) stage_w_async(nextW, sWdst, tid);
    float hv[2][4][4];
#pragma unroll
    for (int rr = 0; rr < 2; rr++)
#pragma unroll
        for (int pt = 0; pt < 4; pt++)
#pragma unroll
            for (int r = 0; r < 4; r++) {
                const int n = wv * 32 + rr * 16 + g * 4 + r;
                hv[rr][pt][r] = tanh_fast(acc[rr][pt][r] + bias[n]);
            }
#pragma unroll
    for (int rr = 0; rr < 2; rr++)
#pragma unroll
        for (int pt = 0; pt < 4; pt++) {
            const int row = pt * 16 + l15;
            *(uint2*)&sHv[row * 128 + SWZ(wv * 32 + rr * 16 + g * 4, row)] =
                pack4h(hv[rr][pt][0], hv[rr][pt][1], hv[rr][pt][2], hv[rr][pt][3]);
        }
}

// 6-dual-channel hidden layer over 16 points, wave = 32-row tile. Same protocol.
__device__ __forceinline__ void hidden_res(const _Float16* sW, _Float16* sH6,
                                           const float* bias,
                                           const unsigned short* nextW, _Float16* sWdst,
                                           int tid, int wv, int g, int l15) {
    f32x4 acc[2][6];
#pragma unroll
    for (int rr = 0; rr < 2; rr++)
#pragma unroll
        for (int c = 0; c < 6; c++) acc[rr][c] = (f32x4){0.f, 0.f, 0.f, 0.f};
#pragma unroll
    for (int ks = 0; ks < 4; ks++) {
        const int ee = SWZ(ks * 32 + g * 8, l15);
        const f16x8 A0 = *(const f16x8*)&sW[(wv * 32 + l15) * 128 + ee];
        const f16x8 A1 = *(const f16x8*)&sW[(wv * 32 + 16 + l15) * 128 + ee];
#pragma unroll
        for (int c = 0; c < 6; c++) {
            const f16x8 Bv = *(const f16x8*)&sH6[c * 2048 + l15 * 128 + ee];
            acc[0][c] = MFMA16(A0, Bv, acc[0][c], 0, 0, 0);
            acc[1][c] = MFMA16(A1, Bv, acc[1][c], 0, 0, 0);
        }
    }
    __syncthreads();  // all sW & sH6 reads complete
    if (nextW) stage_w_async(nextW, sWdst, tid);
    float ch[2][6][4];
#pragma unroll
    for (int rr = 0; rr < 2; rr++)
#pragma unroll
        for (int r = 0; r < 4; r++) {
            const int n = wv * 32 + rr * 16 + g * 4 + r;
            const float z0 = acc[rr][0][r] + bias[n];
            const float a = tanh_fast(z0);
            const float s = 1.f - a * a;
            const float zx = acc[rr][1][r], zy = acc[rr][2][r];
            ch[rr][0][r] = a;
            ch[rr][1][r] = s * zx;
            ch[rr][2][r] = s * zy;
            ch[rr][3][r] = s * acc[rr][3][r];
            ch[rr][4][r] = s * acc[rr][4][r] - 2.f * a * s * zx * zx;
            ch[rr][5][r] = s * acc[rr][5][r] - 2.f * a * s * zy * zy;
        }
#pragma unroll
    for (int rr = 0; rr < 2; rr++) {
        const int eo = l15 * 128 + SWZ(wv * 32 + rr * 16 + g * 4, l15);
#pragma unroll
        for (int c = 0; c < 6; c++)
            *(uint2*)&sH6[c * 2048 + eo] =
                pack4h(ch[rr][c][0], ch[rr][c][1], ch[rr][c][2], ch[rr][c][3]);
    }
}

// ================= fused kernel (256 threads, ~66 KB LDS -> 2 blocks/CU) =================
__global__ __launch_bounds__(BLK) void k_fused(
    const float* __restrict__ xtr, const float* __restrict__ xin,
    const float* __restrict__ icg,
    const float* __restrict__ mw0, const float* __restrict__ mb0,
    const float* __restrict__ mb1, const float* __restrict__ mb2,
    const float* __restrict__ mb3,
    const float* __restrict__ nw0, const float* __restrict__ nb0,
    const float* __restrict__ nb1, const float* __restrict__ nb2,
    const float* __restrict__ nw3, const float* __restrict__ nb3,
    const unsigned short* __restrict__ wt1, const unsigned short* __restrict__ wt2,
    const unsigned short* __restrict__ nt1, const unsigned short* __restrict__ nt2,
    const unsigned short* __restrict__ w3t,
    float* __restrict__ resPart, float* __restrict__ muPart,
    float* __restrict__ icPart) {
    __shared__ __align__(16) _Float16 sW[16384];     // 32 KB, restaged per layer
    __shared__ __align__(16) _Float16 sH[6 * 2048];  // 24 KB; first 16 KB doubles as [64][128] value-H
    __shared__ __align__(16) _Float16 sA[2048];      // 4 KB: nV (mu) then W3m (ic/residual)
    __shared__ __align__(16) float sO[384];          // [ch][pt16][k]
    __shared__ float sB[520];  // mb1@0 mb2@128 mb3@256 | nb1@260 nb2@388 nb3@516
    __shared__ float sMu[128];
    __shared__ float sTq[16];
    __shared__ float sRed[NW][8];

    const int tid = threadIdx.x;
    const int lane = tid & 63, wv = tid >> 6;
    const int g = lane >> 4, l15 = lane & 15;
    const int p16 = tid & 15, chunk = tid >> 4;

    // ---------- prologue: launch W1n stage, fill smalls ----------
    stage_w_async(nt1, sW, tid);
    if (tid < 128) { sB[tid] = mb1[tid]; sB[260 + tid] = nb1[tid]; }
    else           { sB[tid] = mb2[tid - 128]; sB[260 + tid] = nb2[tid - 128]; }
    if (tid < 4) sB[256 + tid] = mb3[tid];
    if (tid == 4) sB[516] = nb3[0];
    if (tid < 16) {
        const int k = tid & 3, q = tid >> 2;
        const int row = (q == 0) ? 1 : ((q == 1) ? 3 : ((q == 2) ? 0 : 2));
        const int pc = (k == 0) ? 0 : ((k == 1) ? 3 : ((k == 2) ? 1 : 2));
        sTq[q * 4 + k] = icg[row * 4 + pc];
    }
    // nV: zeros with nw3 in row 0 (row-0 swizzle key = 0, so unswizzled).
    // NOTE: VALUE conversion, not bit-pattern store (round-8 bug: f2hb here
    // numeric-converted the bit pattern -> weights ~1e4 -> loss ~3.8e16).
    for (int i = tid; i < 2048; i += BLK) sA[i] = (_Float16)0.f;
    if (tid < 128) sA[tid] = (_Float16)nw3[tid];  // same thread zeroed sA[tid] above

    float wxr[8], wyr[8], wzr[8], wbr[8];
#pragma unroll
    for (int j = 0; j < 8; j++) {
        const int n = chunk * 8 + j;
        wxr[j] = nw0[n]; wyr[j] = nw0[128 + n]; wzr[j] = nw0[256 + n]; wbr[j] = nb0[n];
    }

    // ---------- mu: 2 batches x 64 training points ----------
    float accMu2 = 0.f;
    for (int bt = 0; bt < 2; bt++) {
        const int pt0 = blockIdx.x * 128 + bt * 64;
        const int ee0 = SWZ(chunk * 8, p16);
#pragma unroll
        for (int pp = 0; pp < 4; pp++) {
            const int p = pt0 + pp * 16 + p16;
            const float x = xtr[p * 3 + 0], y = xtr[p * 3 + 1], t = xtr[p * 3 + 2];
            float hv[8];
#pragma unroll
            for (int j = 0; j < 8; j++)
                hv[j] = tanh_fast(fmaf(wxr[j], x, fmaf(wyr[j], y, fmaf(wzr[j], t, wbr[j]))));
            const uint2 lo = pack4h(hv[0], hv[1], hv[2], hv[3]);
            const uint2 hi = pack4h(hv[4], hv[5], hv[6], hv[7]);
            *(uint4*)&sH[(pp * 16 + p16) * 128 + ee0] = make_uint4(lo.x, lo.y, hi.x, hi.y);
        }
        VMCNT0; __syncthreads();  // W1n + H ready
        hidden_val(sW, sH, &sB[260], nt2, sW, tid, wv, g, l15);
        VMCNT0; __syncthreads();  // W2n + H ready
        hidden_val(sW, sH, &sB[388], (bt == 0) ? nt1 : wt1, sW, tid, wv, g, l15);
        __syncthreads();          // H2 ready (W loads stay in flight)
        // final 128->1 via MFMA against nV; wave wv handles pt-tile wv
        {
            f32x4 a4 = (f32x4){0.f, 0.f, 0.f, 0.f};
#pragma unroll
            for (int ks = 0; ks < 4; ks++) {
                const int ee = SWZ(ks * 32 + g * 8, l15);
                const f16x8 Af = *(const f16x8*)&sA[l15 * 128 + ee];
                const f16x8 Bv = *(const f16x8*)&sH[(wv * 16 + l15) * 128 + ee];
                a4 = MFMA16(Af, Bv, a4, 0, 0, 0);
            }
            if (g == 0) {  // row 0 = output, point l15
                const float o = a4[0] + sB[516];
                const float muv = 0.01f * o * o;
                sMu[bt * 64 + wv * 16 + l15] = muv;
                accMu2 += muv * muv;
            }
        }
        __syncthreads();  // sH reads done before next overwrite
    }
    accMu2 = wave_allsum(accMu2);
    if (lane == 0) sRed[wv][0] = accMu2;
    __syncthreads();
    if (tid == 0)
        muPart[blockIdx.x] = sRed[0][0] + sRed[1][0] + sRed[2][0] + sRed[3][0];

    // ---------- switch to m-net layer-0 weights ----------
#pragma unroll
    for (int j = 0; j < 8; j++) {
        const int n = chunk * 8 + j;
        wxr[j] = mw0[n]; wyr[j] = mw0[128 + n]; wzr[j] = mw0[256 + n]; wbr[j] = mb0[n];
    }

    // ---------- IC: one batch of 64 initial points ----------
    {
        const int pt0 = blockIdx.x * 64;
        const int ee0 = SWZ(chunk * 8, p16);
#pragma unroll
        for (int pp = 0; pp < 4; pp++) {
            const int p = pt0 + pp * 16 + p16;
            const float x = xin[p * 3 + 0], y = xin[p * 3 + 1], t = xin[p * 3 + 2];
            float hv[8];
#pragma unroll
            for (int j = 0; j < 8; j++)
                hv[j] = tanh_fast(fmaf(wxr[j], x, fmaf(wyr[j], y, fmaf(wzr[j], t, wbr[j]))));
            const uint2 lo = pack4h(hv[0], hv[1], hv[2], hv[3]);
            const uint2 hi = pack4h(hv[4], hv[5], hv[6], hv[7]);
            *(uint4*)&sH[(pp * 16 + p16) * 128 + ee0] = make_uint4(lo.x, lo.y, hi.x, hi.y);
        }
        VMCNT0; __syncthreads();  // W1m + H ready
        hidden_val(sW, sH, &sB[0], wt2, sW, tid, wv, g, l15);
        // stage W3m into sA (nV no longer needed; visible at next barrier)
        ((uint4*)sA)[tid] = ((const uint4*)w3t)[tid];
        VMCNT0; __syncthreads();  // W2m + H + sA ready
        hidden_val(sW, sH, &sB[128], wt1, sW, tid, wv, g, l15);  // W1m for residual b0
        __syncthreads();
        float qs[4] = {0, 0, 0, 0}, qc[4] = {0, 0, 0, 0};
        {
            f32x4 a4 = (f32x4){0.f, 0.f, 0.f, 0.f};
#pragma unroll
            for (int ks = 0; ks < 4; ks++) {
                const int ee = SWZ(ks * 32 + g * 8, l15);
                const f16x8 Af = *(const f16x8*)&sA[l15 * 128 + ee];
                const f16x8 Bv = *(const f16x8*)&sH[(wv * 16 + l15) * 128 + ee];
                a4 = MFMA16(Af, Bv, a4, 0, 0, 0);
            }
            if (g == 0) {
                const int p = pt0 + wv * 16 + l15;
                const float o0 = a4[0] + sB[256];
                const float o1 = a4[1] + sB[257];
                const float o2 = a4[2] + sB[258];
                const float o3 = a4[3] + sB[259];
                const float x = xin[p * 3 + 0];
                const float y = xin[p * 3 + 1];
                int quad = -1;
                if (x < 0.5f && y > 0.5f) quad = 0;
                else if (x > 0.5f && y > 0.5f) quad = 1;
                else if (x < 0.5f && y < 0.5f) quad = 2;
                else if (x > 0.5f && y < 0.5f) quad = 3;
                if (quad >= 0) {
                    const float d0 = o0 - sTq[quad * 4 + 0];
                    const float d1 = o1 - sTq[quad * 4 + 1];
                    const float d2 = o2 - sTq[quad * 4 + 2];
                    const float d3 = o3 - sTq[quad * 4 + 3];
                    const float ss = d0 * d0 + d1 * d1 + d2 * d2 + d3 * d3;
#pragma unroll
                    for (int qq = 0; qq < 4; qq++) {
                        qs[qq] += (quad == qq) ? ss : 0.f;
                        qc[qq] += (quad == qq) ? 1.f : 0.f;
                    }
                }
            }
        }
        __syncthreads();  // sH reads done
#pragma unroll
        for (int qq = 0; qq < 4; qq++) {
            qs[qq] = wave_allsum(qs[qq]);
            qc[qq] = wave_allsum(qc[qq]);
        }
        if (lane == 0) {
#pragma unroll
            for (int qq = 0; qq < 4; qq++) { sRed[wv][qq] = qs[qq]; sRed[wv][4 + qq] = qc[qq]; }
        }
        __syncthreads();
        if (tid == 0) {
#pragma unroll
            for (int q = 0; q < 8; q++)
                icPart[blockIdx.x * 8 + q] =
                    sRed[0][q] + sRed[1][q] + sRed[2][q] + sRed[3][q];
        }
        __syncthreads();
    }

    // ---------- residual: 8 batches x 16 training points ----------
    float racc0 = 0.f, racc1 = 0.f, racc2 = 0.f, racc3 = 0.f;
    const int base = blockIdx.x * 128;
    for (int b = 0; b < 8; b++) {
        const int pt0 = base + b * 16;
        // layer 0 (6 dual channels)
        {
            const int p = pt0 + p16;
            const float x = xtr[p * 3 + 0], y = xtr[p * 3 + 1], t = xtr[p * 3 + 2];
            float ch[6][8];
#pragma unroll
            for (int j = 0; j < 8; j++) {
                const float z = fmaf(wxr[j], x, fmaf(wyr[j], y, fmaf(wzr[j], t, wbr[j])));
                const float a = tanh_fast(z);
                const float s = 1.f - a * a;
                ch[0][j] = a;
                ch[1][j] = s * wxr[j];
                ch[2][j] = s * wyr[j];
                ch[3][j] = s * wzr[j];
                ch[4][j] = -2.f * a * s * wxr[j] * wxr[j];
                ch[5][j] = -2.f * a * s * wyr[j] * wyr[j];
            }
            const int off = p16 * 128 + SWZ(chunk * 8, p16);
#pragma unroll
            for (int c = 0; c < 6; c++) {
                const uint2 lo = pack4h(ch[c][0], ch[c][1], ch[c][2], ch[c][3]);
                const uint2 hi = pack4h(ch[c][4], ch[c][5], ch[c][6], ch[c][7]);
                *(uint4*)&sH[c * 2048 + off] = make_uint4(lo.x, lo.y, hi.x, hi.y);
            }
        }
        VMCNT0; __syncthreads();  // W1m + H ready
        hidden_res(sW, sH, &sB[0], wt2, sW, tid, wv, g, l15);
        VMCNT0; __syncthreads();  // W2m + H ready
        hidden_res(sW, sH, &sB[128],
                   (b < 7) ? wt1 : (const unsigned short*)nullptr, sW, tid, wv, g, l15);
        __syncthreads();
        // final 128->4 per channel: 6 tiles over 4 waves
#pragma unroll
        for (int tt = 0; tt < 2; tt++) {
            const int c = wv + tt * 4;
            if (c < 6) {
                f32x4 a4 = (f32x4){0.f, 0.f, 0.f, 0.f};
#pragma unroll
                for (int ks = 0; ks < 4; ks++) {
                    const int ee = SWZ(ks * 32 + g * 8, l15);
                    const f16x8 Af = *(const f16x8*)&sA[l15 * 128 + ee];
                    const f16x8 Bf = *(const f16x8*)&sH[c * 2048 + l15 * 128 + ee];
                    a4 = MFMA16(Af, Bf, a4, 0, 0, 0);
                }
                if (g == 0) {
                    float4 o = make_float4(a4[0], a4[1], a4[2], a4[3]);
                    if (c == 0) { o.x += sB[256]; o.y += sB[257]; o.z += sB[258]; o.w += sB[259]; }
                    *(float4*)&sO[(c * 16 + l15) * 4] = o;
                }
            }
        }
        __syncthreads();
        // residual math: wave 0 only (lanes redundant x4; lane<16 accumulates)
        if (wv == 0) {
            const int pp = lane & 15;
            const float m = sMu[b * 16 + pp];
            float oq[4][6];
#pragma unroll
            for (int c = 0; c < 6; c++) {
                const float4 o = *(const float4*)&sO[(c * 16 + pp) * 4];
                oq[0][c] = o.x; oq[1][c] = o.y; oq[2][c] = o.z; oq[3][c] = o.w;
            }
            const float rho = oq[0][0], rho_x = oq[0][1], rho_y = oq[0][2],
                        rho_t = oq[0][3], rho_xx = oq[0][4], rho_yy = oq[0][5];
            const float pr = oq[1][0], pr_x = oq[1][1], pr_y = oq[1][2],
                        pr_t = oq[1][3], pr_xx = oq[1][4], pr_yy = oq[1][5];
            const float u = oq[2][0], u_x = oq[2][1], u_y = oq[2][2],
                        u_t = oq[2][3], u_xx = oq[2][4], u_yy = oq[2][5];
            const float v = oq[3][0], v_x = oq[3][1], v_y = oq[3][2],
                        v_t = oq[3][3], v_xx = oq[3][4], v_yy = oq[3][5];

            const float ig1 = 2.5f;
            const float ke = 0.5f * (u * u + v * v);
            const float E = pr * ig1 + rho * ke;
            const float d_x = u * u_x + v * v_x;
            const float d_y = u * u_y + v * v_y;
            const float d_t = u * u_t + v * v_t;
            const float E_x = pr_x * ig1 + rho_x * ke + rho * d_x;
            const float E_y = pr_y * ig1 + rho_y * ke + rho * d_y;
            const float E_t = pr_t * ig1 + rho_t * ke + rho * d_t;
            const float E_xx = pr_xx * ig1 + rho_xx * ke + 2.f * rho_x * d_x +
                               rho * (u_x * u_x + u * u_xx + v_x * v_x + v * v_xx);
            const float E_yy = pr_yy * ig1 + rho_yy * ke + 2.f * rho_y * d_y +
                               rho * (u_y * u_y + u * u_yy + v_y * v_y + v * v_yy);

            const float r1 = rho_t + (rho_x * u + rho * u_x) + (rho_y * v + rho * v_y)
                           - m * (rho_xx + rho_yy);
            const float r2 = (rho_t * u + rho * u_t)
                           + (rho_x * u * u + 2.f * rho * u * u_x + pr_x)
                           + (rho_y * u * v + rho * u_y * v + rho * u * v_y)
                           - m * ((rho_xx * u + 2.f * rho_x * u_x + rho * u_xx)
                                + (rho_yy * u + 2.f * rho_y * u_y + rho * u_yy));
            const float r3 = (rho_t * v + rho * v_t)
                           + (rho_x * u * v + rho * u_x * v + rho * u * v_x)
                           + (rho_y * v * v + 2.f * rho * v * v_y + pr_y)
                           - m * ((rho_xx * v + 2.f * rho_x * v_x + rho * v_xx)
                                + (rho_yy * v + 2.f * rho_y * v_y + rho * v_yy));
            const float r4 = E_t
                           + (u_x * (E + pr) + u * (E_x + pr_x))
                           + (v_y * (E + pr) + v * (E_y + pr_y))
                           - m * (E_xx + E_yy);
            if (lane < 16) {
                racc0 += r1 * r1; racc1 += r2 * r2;
                racc2 += r3 * r3; racc3 += r4 * r4;
            }
        }
        __syncthreads();  // sO/sH reads done before next batch
    }

    if (wv == 0) {
        racc0 = wave_allsum(racc0);
        racc1 = wave_allsum(racc1);
        racc2 = wave_allsum(racc2);
        racc3 = wave_allsum(racc3);
        if (lane == 0) {
            resPart[blockIdx.x * 4 + 0] = racc0;
            resPart[blockIdx.x * 4 + 1] = racc1;
            resPart[blockIdx.x * 4 + 2] = racc2;
            resPart[blockIdx.x * 4 + 3] = racc3;
        }
    }
}

// ---------------- finalize: deterministic fixed-order combine ----------------
__global__ void k_fin(const float* __restrict__ resPart, const float* __restrict__ muPart,
                      const float* __restrict__ icPart, float* __restrict__ out) {
    const int lane = threadIdx.x;
    float r[4] = {0, 0, 0, 0};
    float m2 = 0.f;
    float qs[4] = {0, 0, 0, 0}, qc[4] = {0, 0, 0, 0};
    for (int b = lane; b < GRID; b += 64) {
#pragma unroll
        for (int i = 0; i < 4; i++) r[i] += resPart[b * 4 + i];
        m2 += muPart[b];
#pragma unroll
        for (int q = 0; q < 4; q++) {
            qs[q] += icPart[b * 8 + q];
            qc[q] += icPart[b * 8 + 4 + q];
        }
    }
#pragma unroll
    for (int i = 0; i < 4; i++) r[i] = wave_allsum(r[i]);
    m2 = wave_allsum(m2);
#pragma unroll
    for (int q = 0; q < 4; q++) { qs[q] = wave_allsum(qs[q]); qc[q] = wave_allsum(qc[q]); }
    if (lane == 0) {
        const float sumr = (r[0] + r[1] + r[2] + r[3]) / (float)NPTS;
        float init_loss = 0.f;
#pragma unroll
        for (int q = 0; q < 4; q++) init_loss += qs[q] / fmaxf(qc[q], 1.f);
        out[0] = sumr + 10.f * init_loss + 0.1f * (m2 / (float)NPTS);
    }
}

extern "C" void kernel_launch(void* const* d_in, const int* in_sizes, int n_in,
                              void* d_out, int out_size, void* d_ws, size_t ws_size,
                              hipStream_t stream) {
    const float* xtr = (const float*)d_in[0];
    const float* xin = (const float*)d_in[1];
    const float* icg = (const float*)d_in[2];
    const float* mw0 = (const float*)d_in[3];
    const float* mb0 = (const float*)d_in[4];
    const float* mw1 = (const float*)d_in[5];
    const float* mb1 = (const float*)d_in[6];
    const float* mw2 = (const float*)d_in[7];
    const float* mb2 = (const float*)d_in[8];
    const float* mw3 = (const float*)d_in[9];
    const float* mb3 = (const float*)d_in[10];
    const float* nw0 = (const float*)d_in[11];
    const float* nb0 = (const float*)d_in[12];
    const float* nw1 = (const float*)d_in[13];
    const float* nb1 = (const float*)d_in[14];
    const float* nw2 = (const float*)d_in[15];
    const float* nb2 = (const float*)d_in[16];
    const float* nw3 = (const float*)d_in[17];
    const float* nb3 = (const float*)d_in[18];

    float* wsf = (float*)d_ws;
    float* resPart = wsf;                                // 1024 f
    float* muPart = wsf + 1024;                          // 256 f
    float* icPart = wsf + 1280;                          // 2048 f
    unsigned short* wt1 = (unsigned short*)(wsf + 3328); // 16384 u16 each
    unsigned short* wt2 = wt1 + 16384;
    unsigned short* nt1 = wt2 + 16384;
    unsigned short* nt2 = nt1 + 16384;
    unsigned short* w3t = nt2 + 16384;                   // 2048 u16

    k_prep<<<5, 512, 0, stream>>>(mw1, mw2, nw1, nw2, mw3, wt1, wt2, nt1, nt2, w3t);
    k_fused<<<GRID, BLK, 0, stream>>>(xtr, xin, icg,
                                      mw0, mb0, mb1, mb2, mb3,
                                      nw0, nb0, nb1, nb2, nw3, nb3,
                                      wt1, wt2, nt1, nt2, w3t,
                                      resPart, muPart, icPart);
    k_fin<<<1, 64, 0, stream>>>(resPart, muPart, icPart, (float*)d_out);
}

// Round 10
// 58.724 us; speedup vs baseline: 1.1950x; 1.1950x over previous
//
#include <hip/hip_runtime.h>

#define NPTS 32768
#define NIC  16384
#define GRID 512
#define BLK  256
#define NW   4

typedef __attribute__((ext_vector_type(8))) _Float16 f16x8;
typedef __attribute__((ext_vector_type(4))) float f32x4;

// element-index XOR swizzle keyed on LDS row (row stride = 128 f16 = 256 B)
#define SWZ(e, r) ((e) ^ (((r) & 7) << 3))
#define MFMA16 __builtin_amdgcn_mfma_f32_16x16x32_f16
#define VMCNT0 asm volatile("s_waitcnt vmcnt(0)" ::: "memory")

__device__ __forceinline__ float tanh_fast(float x) {
    float e = __expf(2.0f * x);
    return 1.0f - 2.0f / (e + 1.0f);
}

__device__ __forceinline__ float wave_allsum(float v) {
#pragma unroll
    for (int off = 32; off > 0; off >>= 1) v += __shfl_xor(v, off, 64);
    return v;
}

__device__ __forceinline__ unsigned short f2hb(float x) {
    return __builtin_bit_cast(unsigned short, (_Float16)x);
}
__device__ __forceinline__ uint2 pack4h(float a, float b, float c, float d) {
    return make_uint2((unsigned)f2hb(a) | ((unsigned)f2hb(b) << 16),
                      (unsigned)f2hb(c) | ((unsigned)f2hb(d) << 16));
}

// async global -> LDS stage of one 32 KB packed weight matrix (256 threads x 8 x 16B)
__device__ __forceinline__ void stage_w_async(const unsigned short* __restrict__ src,
                                              _Float16* dst, int tid) {
    const unsigned int* gp = (const unsigned int*)src;
    unsigned int* lp = (unsigned int*)dst;
#pragma unroll
    for (int k = 0; k < 8; k++) {
        __builtin_amdgcn_global_load_lds(
            (const __attribute__((address_space(1))) unsigned int*)(gp + (tid + k * BLK) * 4),
            (__attribute__((address_space(3))) unsigned int*)(lp + (tid + k * BLK) * 4),
            16, 0, 0);
    }
}

// ---------------- prep (proven): transpose + fp16 + swizzle ----------------
__global__ __launch_bounds__(512) void k_prep(
    const float* __restrict__ mw1, const float* __restrict__ mw2,
    const float* __restrict__ nw1, const float* __restrict__ nw2,
    const float* __restrict__ mw3,
    unsigned short* __restrict__ wt1, unsigned short* __restrict__ wt2,
    unsigned short* __restrict__ nt1, unsigned short* __restrict__ nt2,
    unsigned short* __restrict__ w3t) {
    const int tid = threadIdx.x;
    const int bk = blockIdx.x;
    if (bk == 4) {
        for (int i = tid; i < 2048; i += 512) w3t[i] = 0;
        __syncthreads();
        if (tid < 512) {
            const int j = tid & 127, k = tid >> 7;
            w3t[k * 128 + SWZ(j, k)] = f2hb(mw3[j * 4 + k]);
        }
        return;
    }
    const float* src = (bk == 0) ? mw1 : (bk == 1) ? mw2 : (bk == 2) ? nw1 : nw2;
    unsigned short* dst = (bk == 0) ? wt1 : (bk == 1) ? wt2 : (bk == 2) ? nt1 : nt2;
    __shared__ float sM[128 * 129];
#pragma unroll
    for (int k = 0; k < 32; k++) {
        const int idx = tid + k * 512;
        const int j = idx >> 7, n = idx & 127;
        sM[n * 129 + j] = src[idx];
    }
    __syncthreads();
#pragma unroll
    for (int k = 0; k < 32; k++) {
        const int d = tid + k * 512;
        const int n = d >> 7, js = d & 127;
        const int j = js ^ ((n & 7) << 3);
        dst[d] = f2hb(sM[n * 129 + j]);
    }
}

// value-only hidden layer over PT*16 points, wave = 32-row tile.
// Ends with: barrier; optional async stage of nextW into sWdst; epilogue H writes.
// Caller must do VMCNT0 + __syncthreads() before next consumer.
template <int PT>
__device__ __forceinline__ void hidden_val(const _Float16* sW, _Float16* sHv,
                                           const float* bias,
                                           const unsigned short* nextW, _Float16* sWdst,
                                           int tid, int wv, int g, int l15) {
    f32x4 acc[2][PT];
#pragma unroll
    for (int rr = 0; rr < 2; rr++)
#pragma unroll
        for (int pt = 0; pt < PT; pt++) acc[rr][pt] = (f32x4){0.f, 0.f, 0.f, 0.f};
#pragma unroll
    for (int ks = 0; ks < 4; ks++) {
        const int ee = SWZ(ks * 32 + g * 8, l15);
        const f16x8 A0 = *(const f16x8*)&sW[(wv * 32 + l15) * 128 + ee];
        const f16x8 A1 = *(const f16x8*)&sW[(wv * 32 + 16 + l15) * 128 + ee];
#pragma unroll
        for (int pt = 0; pt < PT; pt++) {
            const f16x8 Bv = *(const f16x8*)&sHv[(pt * 16 + l15) * 128 + ee];
            acc[0][pt] = MFMA16(A0, Bv, acc[0][pt], 0, 0, 0);
            acc[1][pt] = MFMA16(A1, Bv, acc[1][pt], 0, 0, 0);
        }
    }
    __syncthreads();  // all sW & sHv reads complete
    if (nextW) stage_w_async(nextW, sWdst, tid);
    float hv[2][PT][4];
#pragma unroll
    for (int rr = 0; rr < 2; rr++)
#pragma unroll
        for (int pt = 0; pt < PT; pt++)
#pragma unroll
            for (int r = 0; r < 4; r++) {
                const int n = wv * 32 + rr * 16 + g * 4 + r;
                hv[rr][pt][r] = tanh_fast(acc[rr][pt][r] + bias[n]);
            }
#pragma unroll
    for (int rr = 0; rr < 2; rr++)
#pragma unroll
        for (int pt = 0; pt < PT; pt++) {
            const int row = pt * 16 + l15;
            *(uint2*)&sHv[row * 128 + SWZ(wv * 32 + rr * 16 + g * 4, row)] =
                pack4h(hv[rr][pt][0], hv[rr][pt][1], hv[rr][pt][2], hv[rr][pt][3]);
        }
}

// 6-dual-channel hidden layer over 16 points, wave = 32-row tile. Same protocol.
__device__ __forceinline__ void hidden_res(const _Float16* sW, _Float16* sH6,
                                           const float* bias,
                                           const unsigned short* nextW, _Float16* sWdst,
                                           int tid, int wv, int g, int l15) {
    f32x4 acc[2][6];
#pragma unroll
    for (int rr = 0; rr < 2; rr++)
#pragma unroll
        for (int c = 0; c < 6; c++) acc[rr][c] = (f32x4){0.f, 0.f, 0.f, 0.f};
#pragma unroll
    for (int ks = 0; ks < 4; ks++) {
        const int ee = SWZ(ks * 32 + g * 8, l15);
        const f16x8 A0 = *(const f16x8*)&sW[(wv * 32 + l15) * 128 + ee];
        const f16x8 A1 = *(const f16x8*)&sW[(wv * 32 + 16 + l15) * 128 + ee];
#pragma unroll
        for (int c = 0; c < 6; c++) {
            const f16x8 Bv = *(const f16x8*)&sH6[c * 2048 + l15 * 128 + ee];
            acc[0][c] = MFMA16(A0, Bv, acc[0][c], 0, 0, 0);
            acc[1][c] = MFMA16(A1, Bv, acc[1][c], 0, 0, 0);
        }
    }
    __syncthreads();  // all sW & sH6 reads complete
    if (nextW) stage_w_async(nextW, sWdst, tid);
    float ch[2][6][4];
#pragma unroll
    for (int rr = 0; rr < 2; rr++)
#pragma unroll
        for (int r = 0; r < 4; r++) {
            const int n = wv * 32 + rr * 16 + g * 4 + r;
            const float z0 = acc[rr][0][r] + bias[n];
            const float a = tanh_fast(z0);
            const float s = 1.f - a * a;
            const float zx = acc[rr][1][r], zy = acc[rr][2][r];
            ch[rr][0][r] = a;
            ch[rr][1][r] = s * zx;
            ch[rr][2][r] = s * zy;
            ch[rr][3][r] = s * acc[rr][3][r];
            ch[rr][4][r] = s * acc[rr][4][r] - 2.f * a * s * zx * zx;
            ch[rr][5][r] = s * acc[rr][5][r] - 2.f * a * s * zy * zy;
        }
#pragma unroll
    for (int rr = 0; rr < 2; rr++) {
        const int eo = l15 * 128 + SWZ(wv * 32 + rr * 16 + g * 4, l15);
#pragma unroll
        for (int c = 0; c < 6; c++)
            *(uint2*)&sH6[c * 2048 + eo] =
                pack4h(ch[rr][c][0], ch[rr][c][1], ch[rr][c][2], ch[rr][c][3]);
    }
}

// ====== fused kernel (512 blocks x 256 threads, ~66 KB LDS -> 2 blocks/CU) ======
__global__ __launch_bounds__(BLK) void k_fused(
    const float* __restrict__ xtr, const float* __restrict__ xin,
    const float* __restrict__ icg,
    const float* __restrict__ mw0, const float* __restrict__ mb0,
    const float* __restrict__ mb1, const float* __restrict__ mb2,
    const float* __restrict__ mb3,
    const float* __restrict__ nw0, const float* __restrict__ nb0,
    const float* __restrict__ nb1, const float* __restrict__ nb2,
    const float* __restrict__ nw3, const float* __restrict__ nb3,
    const unsigned short* __restrict__ wt1, const unsigned short* __restrict__ wt2,
    const unsigned short* __restrict__ nt1, const unsigned short* __restrict__ nt2,
    const unsigned short* __restrict__ w3t,
    float* __restrict__ resPart, float* __restrict__ muPart,
    float* __restrict__ icPart) {
    __shared__ __align__(16) _Float16 sW[16384];     // 32 KB, restaged per layer
    __shared__ __align__(16) _Float16 sH[6 * 2048];  // 24 KB; first 16 KB doubles as [64][128] value-H
    __shared__ __align__(16) _Float16 sA[2048];      // 4 KB: nV (mu) then W3m (ic/residual)
    __shared__ __align__(16) float sO[384];          // [ch][pt16][k]
    __shared__ float sB[520];  // mb1@0 mb2@128 mb3@256 | nb1@260 nb2@388 nb3@516
    __shared__ float sMu[64];
    __shared__ float sTq[16];
    __shared__ float sRed[NW][8];

    const int tid = threadIdx.x;
    const int lane = tid & 63, wv = tid >> 6;
    const int g = lane >> 4, l15 = lane & 15;
    const int p16 = tid & 15, chunk = tid >> 4;

    // ---------- prologue: launch W1n stage, fill smalls ----------
    stage_w_async(nt1, sW, tid);
    if (tid < 128) { sB[tid] = mb1[tid]; sB[260 + tid] = nb1[tid]; }
    else           { sB[tid] = mb2[tid - 128]; sB[260 + tid] = nb2[tid - 128]; }
    if (tid < 4) sB[256 + tid] = mb3[tid];
    if (tid == 4) sB[516] = nb3[0];
    if (tid < 16) {
        const int k = tid & 3, q = tid >> 2;
        const int row = (q == 0) ? 1 : ((q == 1) ? 3 : ((q == 2) ? 0 : 2));
        const int pc = (k == 0) ? 0 : ((k == 1) ? 3 : ((k == 2) ? 1 : 2));
        sTq[q * 4 + k] = icg[row * 4 + pc];
    }
    // nV: zeros with nw3 in row 0 (row-0 swizzle key = 0 -> unswizzled).
    // VALUE conversion (round-8 bug was a bit-pattern int->fp16 convert here).
    for (int i = tid; i < 2048; i += BLK) sA[i] = (_Float16)0.f;
    if (tid < 128) sA[tid] = (_Float16)nw3[tid];  // same thread zeroed sA[tid] above

    float wxr[8], wyr[8], wzr[8], wbr[8];
#pragma unroll
    for (int j = 0; j < 8; j++) {
        const int n = chunk * 8 + j;
        wxr[j] = nw0[n]; wyr[j] = nw0[128 + n]; wzr[j] = nw0[256 + n]; wbr[j] = nb0[n];
    }

    // ---------- mu: one batch of 64 training points ----------
    float accMu2 = 0.f;
    {
        const int pt0 = blockIdx.x * 64;
        const int ee0 = SWZ(chunk * 8, p16);
#pragma unroll
        for (int pp = 0; pp < 4; pp++) {
            const int p = pt0 + pp * 16 + p16;
            const float x = xtr[p * 3 + 0], y = xtr[p * 3 + 1], t = xtr[p * 3 + 2];
            float hv[8];
#pragma unroll
            for (int j = 0; j < 8; j++)
                hv[j] = tanh_fast(fmaf(wxr[j], x, fmaf(wyr[j], y, fmaf(wzr[j], t, wbr[j]))));
            const uint2 lo = pack4h(hv[0], hv[1], hv[2], hv[3]);
            const uint2 hi = pack4h(hv[4], hv[5], hv[6], hv[7]);
            *(uint4*)&sH[(pp * 16 + p16) * 128 + ee0] = make_uint4(lo.x, lo.y, hi.x, hi.y);
        }
        VMCNT0; __syncthreads();  // W1n + H ready
        hidden_val<4>(sW, sH, &sB[260], nt2, sW, tid, wv, g, l15);
        VMCNT0; __syncthreads();  // W2n + H ready
        hidden_val<4>(sW, sH, &sB[388], wt1, sW, tid, wv, g, l15);
        __syncthreads();          // H2 ready (W1m load stays in flight)
        // final 128->1 via MFMA against nV; wave wv handles pt-tile wv
        {
            f32x4 a4 = (f32x4){0.f, 0.f, 0.f, 0.f};
#pragma unroll
            for (int ks = 0; ks < 4; ks++) {
                const int ee = SWZ(ks * 32 + g * 8, l15);
                const f16x8 Af = *(const f16x8*)&sA[l15 * 128 + ee];
                const f16x8 Bv = *(const f16x8*)&sH[(wv * 16 + l15) * 128 + ee];
                a4 = MFMA16(Af, Bv, a4, 0, 0, 0);
            }
            if (g == 0) {  // row 0 = output, point l15
                const float o = a4[0] + sB[516];
                const float muv = 0.01f * o * o;
                sMu[wv * 16 + l15] = muv;
                accMu2 += muv * muv;
            }
        }
        __syncthreads();  // sH reads done before next overwrite
    }
    accMu2 = wave_allsum(accMu2);
    if (lane == 0) sRed[wv][0] = accMu2;
    __syncthreads();
    if (tid == 0)
        muPart[blockIdx.x] = sRed[0][0] + sRed[1][0] + sRed[2][0] + sRed[3][0];

    // ---------- switch to m-net layer-0 weights ----------
#pragma unroll
    for (int j = 0; j < 8; j++) {
        const int n = chunk * 8 + j;
        wxr[j] = mw0[n]; wyr[j] = mw0[128 + n]; wzr[j] = mw0[256 + n]; wbr[j] = mb0[n];
    }

    // ---------- IC: one batch of 32 initial points ----------
    {
        const int pt0 = blockIdx.x * 32;
        const int ee0 = SWZ(chunk * 8, p16);
#pragma unroll
        for (int pp = 0; pp < 2; pp++) {
            const int p = pt0 + pp * 16 + p16;
            const float x = xin[p * 3 + 0], y = xin[p * 3 + 1], t = xin[p * 3 + 2];
            float hv[8];
#pragma unroll
            for (int j = 0; j < 8; j++)
                hv[j] = tanh_fast(fmaf(wxr[j], x, fmaf(wyr[j], y, fmaf(wzr[j], t, wbr[j]))));
            const uint2 lo = pack4h(hv[0], hv[1], hv[2], hv[3]);
            const uint2 hi = pack4h(hv[4], hv[5], hv[6], hv[7]);
            *(uint4*)&sH[(pp * 16 + p16) * 128 + ee0] = make_uint4(lo.x, lo.y, hi.x, hi.y);
        }
        VMCNT0; __syncthreads();  // W1m + H ready
        hidden_val<2>(sW, sH, &sB[0], wt2, sW, tid, wv, g, l15);
        // stage W3m into sA (nV no longer needed; visible at next barrier)
        ((uint4*)sA)[tid] = ((const uint4*)w3t)[tid];
        VMCNT0; __syncthreads();  // W2m + H + sA ready
        hidden_val<2>(sW, sH, &sB[128], wt1, sW, tid, wv, g, l15);  // W1m for residual b0
        __syncthreads();
        float qs[4] = {0, 0, 0, 0}, qc[4] = {0, 0, 0, 0};
        if (wv < 2) {  // 2 pt-tiles, waves 0-1
            f32x4 a4 = (f32x4){0.f, 0.f, 0.f, 0.f};
#pragma unroll
            for (int ks = 0; ks < 4; ks++) {
                const int ee = SWZ(ks * 32 + g * 8, l15);
                const f16x8 Af = *(const f16x8*)&sA[l15 * 128 + ee];
                const f16x8 Bv = *(const f16x8*)&sH[(wv * 16 + l15) * 128 + ee];
                a4 = MFMA16(Af, Bv, a4, 0, 0, 0);
            }
            if (g == 0) {
                const int p = pt0 + wv * 16 + l15;
                const float o0 = a4[0] + sB[256];
                const float o1 = a4[1] + sB[257];
                const float o2 = a4[2] + sB[258];
                const float o3 = a4[3] + sB[259];
                const float x = xin[p * 3 + 0];
                const float y = xin[p * 3 + 1];
                int quad = -1;
                if (x < 0.5f && y > 0.5f) quad = 0;
                else if (x > 0.5f && y > 0.5f) quad = 1;
                else if (x < 0.5f && y < 0.5f) quad = 2;
                else if (x > 0.5f && y < 0.5f) quad = 3;
                if (quad >= 0) {
                    const float d0 = o0 - sTq[quad * 4 + 0];
                    const float d1 = o1 - sTq[quad * 4 + 1];
                    const float d2 = o2 - sTq[quad * 4 + 2];
                    const float d3 = o3 - sTq[quad * 4 + 3];
                    const float ss = d0 * d0 + d1 * d1 + d2 * d2 + d3 * d3;
#pragma unroll
                    for (int qq = 0; qq < 4; qq++) {
                        qs[qq] += (quad == qq) ? ss : 0.f;
                        qc[qq] += (quad == qq) ? 1.f : 0.f;
                    }
                }
            }
        }
        __syncthreads();  // sH reads done
#pragma unroll
        for (int qq = 0; qq < 4; qq++) {
            qs[qq] = wave_allsum(qs[qq]);
            qc[qq] = wave_allsum(qc[qq]);
        }
        if (lane == 0) {
#pragma unroll
            for (int qq = 0; qq < 4; qq++) { sRed[wv][qq] = qs[qq]; sRed[wv][4 + qq] = qc[qq]; }
        }
        __syncthreads();
        if (tid == 0) {
#pragma unroll
            for (int q = 0; q < 8; q++)
                icPart[blockIdx.x * 8 + q] =
                    sRed[0][q] + sRed[1][q] + sRed[2][q] + sRed[3][q];
        }
        __syncthreads();
    }

    // ---------- residual: 4 batches x 16 training points ----------
    float racc0 = 0.f, racc1 = 0.f, racc2 = 0.f, racc3 = 0.f;
    const int base = blockIdx.x * 64;
    for (int b = 0; b < 4; b++) {
        const int pt0 = base + b * 16;
        // layer 0 (6 dual channels)
        {
            const int p = pt0 + p16;
            const float x = xtr[p * 3 + 0], y = xtr[p * 3 + 1], t = xtr[p * 3 + 2];
            float ch[6][8];
#pragma unroll
            for (int j = 0; j < 8; j++) {
                const float z = fmaf(wxr[j], x, fmaf(wyr[j], y, fmaf(wzr[j], t, wbr[j])));
                const float a = tanh_fast(z);
                const float s = 1.f - a * a;
                ch[0][j] = a;
                ch[1][j] = s * wxr[j];
                ch[2][j] = s * wyr[j];
                ch[3][j] = s * wzr[j];
                ch[4][j] = -2.f * a * s * wxr[j] * wxr[j];
                ch[5][j] = -2.f * a * s * wyr[j] * wyr[j];
            }
            const int off = p16 * 128 + SWZ(chunk * 8, p16);
#pragma unroll
            for (int c = 0; c < 6; c++) {
                const uint2 lo = pack4h(ch[c][0], ch[c][1], ch[c][2], ch[c][3]);
                const uint2 hi = pack4h(ch[c][4], ch[c][5], ch[c][6], ch[c][7]);
                *(uint4*)&sH[c * 2048 + off] = make_uint4(lo.x, lo.y, hi.x, hi.y);
            }
        }
        VMCNT0; __syncthreads();  // W1m + H ready
        hidden_res(sW, sH, &sB[0], wt2, sW, tid, wv, g, l15);
        VMCNT0; __syncthreads();  // W2m + H ready
        hidden_res(sW, sH, &sB[128],
                   (b < 3) ? wt1 : (const unsigned short*)nullptr, sW, tid, wv, g, l15);
        __syncthreads();
        // final 128->4 per channel: 6 tiles over 4 waves
#pragma unroll
        for (int tt = 0; tt < 2; tt++) {
            const int c = wv + tt * 4;
            if (c < 6) {
                f32x4 a4 = (f32x4){0.f, 0.f, 0.f, 0.f};
#pragma unroll
                for (int ks = 0; ks < 4; ks++) {
                    const int ee = SWZ(ks * 32 + g * 8, l15);
                    const f16x8 Af = *(const f16x8*)&sA[l15 * 128 + ee];
                    const f16x8 Bf = *(const f16x8*)&sH[c * 2048 + l15 * 128 + ee];
                    a4 = MFMA16(Af, Bf, a4, 0, 0, 0);
                }
                if (g == 0) {
                    float4 o = make_float4(a4[0], a4[1], a4[2], a4[3]);
                    if (c == 0) { o.x += sB[256]; o.y += sB[257]; o.z += sB[258]; o.w += sB[259]; }
                    *(float4*)&sO[(c * 16 + l15) * 4] = o;
                }
            }
        }
        __syncthreads();
        // residual math: wave 0 only (lanes redundant x4; lane<16 accumulates)
        if (wv == 0) {
            const int pp = lane & 15;
            const float m = sMu[b * 16 + pp];
            float oq[4][6];
#pragma unroll
            for (int c = 0; c < 6; c++) {
                const float4 o = *(const float4*)&sO[(c * 16 + pp) * 4];
                oq[0][c] = o.x; oq[1][c] = o.y; oq[2][c] = o.z; oq[3][c] = o.w;
            }
            const float rho = oq[0][0], rho_x = oq[0][1], rho_y = oq[0][2],
                        rho_t = oq[0][3], rho_xx = oq[0][4], rho_yy = oq[0][5];
            const float pr = oq[1][0], pr_x = oq[1][1], pr_y = oq[1][2],
                        pr_t = oq[1][3], pr_xx = oq[1][4], pr_yy = oq[1][5];
            const float u = oq[2][0], u_x = oq[2][1], u_y = oq[2][2],
                        u_t = oq[2][3], u_xx = oq[2][4], u_yy = oq[2][5];
            const float v = oq[3][0], v_x = oq[3][1], v_y = oq[3][2],
                        v_t = oq[3][3], v_xx = oq[3][4], v_yy = oq[3][5];

            const float ig1 = 2.5f;
            const float ke = 0.5f * (u * u + v * v);
            const float E = pr * ig1 + rho * ke;
            const float d_x = u * u_x + v * v_x;
            const float d_y = u * u_y + v * v_y;
            const float d_t = u * u_t + v * v_t;
            const float E_x = pr_x * ig1 + rho_x * ke + rho * d_x;
            const float E_y = pr_y * ig1 + rho_y * ke + rho * d_y;
            const float E_t = pr_t * ig1 + rho_t * ke + rho * d_t;
            const float E_xx = pr_xx * ig1 + rho_xx * ke + 2.f * rho_x * d_x +
                               rho * (u_x * u_x + u * u_xx + v_x * v_x + v * v_xx);
            const float E_yy = pr_yy * ig1 + rho_yy * ke + 2.f * rho_y * d_y +
                               rho * (u_y * u_y + u * u_yy + v_y * v_y + v * v_yy);

            const float r1 = rho_t + (rho_x * u + rho * u_x) + (rho_y * v + rho * v_y)
                           - m * (rho_xx + rho_yy);
            const float r2 = (rho_t * u + rho * u_t)
                           + (rho_x * u * u + 2.f * rho * u * u_x + pr_x)
                           + (rho_y * u * v + rho * u_y * v + rho * u * v_y)
                           - m * ((rho_xx * u + 2.f * rho_x * u_x + rho * u_xx)
                                + (rho_yy * u + 2.f * rho_y * u_y + rho * u_yy));
            const float r3 = (rho_t * v + rho * v_t)
                           + (rho_x * u * v + rho * u_x * v + rho * u * v_x)
                           + (rho_y * v * v + 2.f * rho * v * v_y + pr_y)
                           - m * ((rho_xx * v + 2.f * rho_x * v_x + rho * v_xx)
                                + (rho_yy * v + 2.f * rho_y * v_y + rho * v_yy));
            const float r4 = E_t
                           + (u_x * (E + pr) + u * (E_x + pr_x))
                           + (v_y * (E + pr) + v * (E_y + pr_y))
                           - m * (E_xx + E_yy);
            if (lane < 16) {
                racc0 += r1 * r1; racc1 += r2 * r2;
                racc2 += r3 * r3; racc3 += r4 * r4;
            }
        }
        __syncthreads();  // sO/sH reads done before next batch
    }

    if (wv == 0) {
        racc0 = wave_allsum(racc0);
        racc1 = wave_allsum(racc1);
        racc2 = wave_allsum(racc2);
        racc3 = wave_allsum(racc3);
        if (lane == 0) {
            resPart[blockIdx.x * 4 + 0] = racc0;
            resPart[blockIdx.x * 4 + 1] = racc1;
            resPart[blockIdx.x * 4 + 2] = racc2;
            resPart[blockIdx.x * 4 + 3] = racc3;
        }
    }
}

// ---------------- finalize: deterministic fixed-order combine ----------------
__global__ void k_fin(const float* __restrict__ resPart, const float* __restrict__ muPart,
                      const float* __restrict__ icPart, float* __restrict__ out) {
    const int lane = threadIdx.x;
    float r[4] = {0, 0, 0, 0};
    float m2 = 0.f;
    float qs[4] = {0, 0, 0, 0}, qc[4] = {0, 0, 0, 0};
    for (int b = lane; b < GRID; b += 64) {
#pragma unroll
        for (int i = 0; i < 4; i++) r[i] += resPart[b * 4 + i];
        m2 += muPart[b];
#pragma unroll
        for (int q = 0; q < 4; q++) {
            qs[q] += icPart[b * 8 + q];
            qc[q] += icPart[b * 8 + 4 + q];
        }
    }
#pragma unroll
    for (int i = 0; i < 4; i++) r[i] = wave_allsum(r[i]);
    m2 = wave_allsum(m2);
#pragma unroll
    for (int q = 0; q < 4; q++) { qs[q] = wave_allsum(qs[q]); qc[q] = wave_allsum(qc[q]); }
    if (lane == 0) {
        const float sumr = (r[0] + r[1] + r[2] + r[3]) / (float)NPTS;
        float init_loss = 0.f;
#pragma unroll
        for (int q = 0; q < 4; q++) init_loss += qs[q] / fmaxf(qc[q], 1.f);
        out[0] = sumr + 10.f * init_loss + 0.1f * (m2 / (float)NPTS);
    }
}

extern "C" void kernel_launch(void* const* d_in, const int* in_sizes, int n_in,
                              void* d_out, int out_size, void* d_ws, size_t ws_size,
                              hipStream_t stream) {
    const float* xtr = (const float*)d_in[0];
    const float* xin = (const float*)d_in[1];
    const float* icg = (const float*)d_in[2];
    const float* mw0 = (const float*)d_in[3];
    const float* mb0 = (const float*)d_in[4];
    const float* mw1 = (const float*)d_in[5];
    const float* mb1 = (const float*)d_in[6];
    const float* mw2 = (const float*)d_in[7];
    const float* mb2 = (const float*)d_in[8];
    const float* mw3 = (const float*)d_in[9];
    const float* mb3 = (const float*)d_in[10];
    const float* nw0 = (const float*)d_in[11];
    const float* nb0 = (const float*)d_in[12];
    const float* nw1 = (const float*)d_in[13];
    const float* nb1 = (const float*)d_in[14];
    const float* nw2 = (const float*)d_in[15];
    const float* nb2 = (const float*)d_in[16];
    const float* nw3 = (const float*)d_in[17];
    const float* nb3 = (const float*)d_in[18];

    float* wsf = (float*)d_ws;
    float* resPart = wsf;                                // 2048 f
    float* muPart = wsf + 2048;                          // 512 f
    float* icPart = wsf + 2560;                          // 4096 f
    unsigned short* wt1 = (unsigned short*)(wsf + 6656); // 16384 u16 each
    unsigned short* wt2 = wt1 + 16384;
    unsigned short* nt1 = wt2 + 16384;
    unsigned short* nt2 = nt1 + 16384;
    unsigned short* w3t = nt2 + 16384;                   // 2048 u16

    k_prep<<<5, 512, 0, stream>>>(mw1, mw2, nw1, nw2, mw3, wt1, wt2, nt1, nt2, w3t);
    k_fused<<<GRID, BLK, 0, stream>>>(xtr, xin, icg,
                                      mw0, mb0, mb1, mb2, mb3,
                                      nw0, nb0, nb1, nb2, nw3, nb3,
                                      wt1, wt2, nt1, nt2, w3t,
                                      resPart, muPart, icPart);
    k_fin<<<1, 64, 0, stream>>>(resPart, muPart, icPart, (float*)d_out);
}